// Round 1
// baseline (433.930 us; speedup 1.0000x reference)
//
#include <hip/hip_runtime.h>
#include <hip/hip_bf16.h>
#include <hip/hip_fp16.h>
#include <stdint.h>

#define DI __device__ __forceinline__

typedef __bf16 bf16x4 __attribute__((ext_vector_type(4)));
typedef __bf16 bf16x8 __attribute__((ext_vector_type(8)));
typedef float  f32x4  __attribute__((ext_vector_type(4)));

static constexpr int  BATCH = 4;
static constexpr int  SEQ   = 4096;
static constexpr int  DIM   = 768;
static constexpr long TOK   = (long)BATCH * SEQ;        // 16384
static constexpr int  QT    = SEQ / 128;                // 32 q-tiles per batch
static constexpr int  NTRI  = QT * (QT + 1) / 2;        // 528 causal tiles
static constexpr float SCALE = 0.0360843918243516150f;  // 1/sqrt(768)
static constexpr float NEGS  = -30000.0f;               // fp16-safe "-inf" logit

// ---------------- fp32 -> bf16 convert (vectorized) ----------------
__global__ void cvt_kernel(const float* __restrict__ in, __bf16* __restrict__ out, long n4){
  long i = (long)blockIdx.x * blockDim.x + threadIdx.x;
  const long stride = (long)gridDim.x * blockDim.x;
  for(; i < n4; i += stride){
    float4 v = ((const float4*)in)[i];
    bf16x4 o = { (__bf16)v.x, (__bf16)v.y, (__bf16)v.z, (__bf16)v.w };
    ((bf16x4*)out)[i] = o;
  }
}

// ---------------- shared GEMM machinery ----------------
// LDS tile: [128 rows][64 bf16 = 8 chunks of 16B], chunk position XOR-swizzled by (row&7).
DI int swz_off(int r, int c){ return (r << 7) + ((c ^ (r & 7)) << 4); }

// Stage a 128x64 bf16 tile from row-major src (leading dim ld) via global_load_lds.
// LDS dest is linear (wave-uniform base + lane*16); swizzle achieved by pre-swizzling
// the per-lane GLOBAL source chunk (m173 pattern).
DI void stage_tile(const __bf16* __restrict__ src, long ld, char* lds, int tid){
  const int w = tid >> 6, l = tid & 63;
  const int rsub = l >> 3;                 // row-within-8  (== r&7 for every iter)
  const int kc   = (l & 7) ^ rsub;         // swizzled source chunk
  const __bf16* g = src + (long)(w * 8 + rsub) * ld + kc * 8;
  char* d = lds + (w << 10);
  #pragma unroll
  for(int i = 0; i < 4; ++i){
    __builtin_amdgcn_global_load_lds(
        (const __attribute__((address_space(1))) void*)(g + (long)(i * 32) * ld),
        (__attribute__((address_space(3))) void*)(d + (i << 12)), 16, 0, 0);
  }
}

DI bf16x8 frag_ld(const char* lds, int row, int c){
  return *(const bf16x8*)(lds + swz_off(row, c));
}

// One K=64 step: 32 MFMAs per wave (4x4 frags x 2 k-halves).
DI void mma_tile(const char* As, const char* Bs, int lane, int wr, int wc, f32x4 acc[4][4]){
  #pragma unroll
  for(int kk = 0; kk < 2; ++kk){
    const int c = kk * 4 + (lane >> 4);
    bf16x8 a[4], b[4];
    #pragma unroll
    for(int i = 0; i < 4; ++i) a[i] = frag_ld(As, wr + i * 16 + (lane & 15), c);
    #pragma unroll
    for(int j = 0; j < 4; ++j) b[j] = frag_ld(Bs, wc + j * 16 + (lane & 15), c);
    #pragma unroll
    for(int i = 0; i < 4; ++i)
      #pragma unroll
      for(int j = 0; j < 4; ++j)
        acc[i][j] = __builtin_amdgcn_mfma_f32_16x16x32_bf16(a[i], b[j], acc[i][j], 0, 0, 0);
  }
}

// C[m][n] = sum_k A[m][k]*B[n][k] + bias   (torch Linear / B-transposed form)
// grid: x = n-tile, y = m-tile. All dims multiples of 128; K multiple of 64.
template<bool OUTF32, bool BIASM>
__global__ __launch_bounds__(256)
void gemm_bt(const __bf16* __restrict__ A, const __bf16* __restrict__ B,
             const float* __restrict__ bias, void* __restrict__ C,
             int K, long lda, long ldb, long ldc){
  __shared__ __attribute__((aligned(128))) char As[16384];
  __shared__ __attribute__((aligned(128))) char Bs[16384];
  const int tid = threadIdx.x, lane = tid & 63, w = tid >> 6;
  const int wr = (w >> 1) * 64, wc = (w & 1) * 64;
  const long m0 = (long)blockIdx.y * 128, n0 = (long)blockIdx.x * 128;
  f32x4 acc[4][4] = {};
  for(int k0 = 0; k0 < K; k0 += 64){
    stage_tile(A + m0 * lda + k0, lda, As, tid);
    stage_tile(B + n0 * ldb + k0, ldb, Bs, tid);
    __syncthreads();
    mma_tile(As, Bs, lane, wr, wc, acc);
    __syncthreads();
  }
  const int cl = lane & 15, rq = (lane >> 4) * 4;
  #pragma unroll
  for(int i = 0; i < 4; ++i)
    #pragma unroll
    for(int j = 0; j < 4; ++j){
      const long gc = n0 + wc + j * 16 + cl;
      #pragma unroll
      for(int e = 0; e < 4; ++e){
        const long gr = m0 + wr + i * 16 + rq + e;
        float v = acc[i][j][e] + (BIASM ? bias[gr] : bias[gc]);
        if(OUTF32) ((float*)C)[gr * ldc + gc] = v;
        else       ((__bf16*)C)[gr * ldc + gc] = (__bf16)v;
      }
    }
}

// ---------------- QK^T (causal, block-compacted fp16 output) ----------------
__global__ __launch_bounds__(256)
void qk_kernel(const __bf16* __restrict__ qb, const __bf16* __restrict__ kb,
               __half* __restrict__ Sc){
  const int b = blockIdx.y;
  const int t = blockIdx.x;                       // 0..527 lower-tri tile id
  int qi = (int)((sqrtf(8.0f * t + 1.0f) - 1.0f) * 0.5f);
  while((qi + 1) * (qi + 2) / 2 <= t) qi++;
  while(qi * (qi + 1) / 2 > t) qi--;
  const int ki = t - qi * (qi + 1) / 2;
  const __bf16* Aq = qb + (long)b * SEQ * DIM + (long)qi * 128 * DIM;
  const __bf16* Bk = kb + (long)b * SEQ * DIM + (long)ki * 128 * DIM;
  __shared__ __attribute__((aligned(128))) char As[16384];
  __shared__ __attribute__((aligned(128))) char Bs[16384];
  const int tid = threadIdx.x, lane = tid & 63, w = tid >> 6;
  const int wr = (w >> 1) * 64, wc = (w & 1) * 64;
  f32x4 acc[4][4] = {};
  for(int k0 = 0; k0 < DIM; k0 += 64){
    stage_tile(Aq + k0, DIM, As, tid);
    stage_tile(Bk + k0, DIM, Bs, tid);
    __syncthreads();
    mma_tile(As, Bs, lane, wr, wc, acc);
    __syncthreads();
  }
  __half* tile = Sc + (long)b * NTRI * 16384 + (long)t * 16384;
  const int cl = lane & 15, rq = (lane >> 4) * 4;
  const bool diag = (qi == ki);
  #pragma unroll
  for(int i = 0; i < 4; ++i)
    #pragma unroll
    for(int j = 0; j < 4; ++j){
      const int c = wc + j * 16 + cl;
      #pragma unroll
      for(int e = 0; e < 4; ++e){
        const int r = wr + i * 16 + rq + e;
        float v = acc[i][j][e] * SCALE;
        if(diag && c > r) v = NEGS;
        tile[r * 128 + c] = (__half)v;
      }
    }
}

// ---------------- per-row softmax stats: m = rowmax, rl = 1/rowsum(exp) ----------------
__global__ void rowstats(const __half* __restrict__ Sc, float* __restrict__ mrow,
                         float* __restrict__ rlrow){
  const int gr = blockIdx.x * 4 + (threadIdx.x >> 6);   // one wave per row
  const int lane = threadIdx.x & 63;
  const int b = gr >> 12, r = gr & 4095;
  const int qi = r >> 7, rloc = r & 127;
  const __half* base = Sc + (long)b * NTRI * 16384 + (long)(qi * (qi + 1) / 2) * 16384
                       + rloc * 128;
  float mx = -1e30f;
  for(int ki = 0; ki <= qi; ++ki){
    float2 v = __half22float2(*((const __half2*)(base + (long)ki * 16384) + lane));
    mx = fmaxf(mx, fmaxf(v.x, v.y));
  }
  #pragma unroll
  for(int off = 32; off; off >>= 1) mx = fmaxf(mx, __shfl_xor(mx, off));
  float sum = 0.f;
  for(int ki = 0; ki <= qi; ++ki){
    float2 v = __half22float2(*((const __half2*)(base + (long)ki * 16384) + lane));
    sum += __expf(v.x - mx) + __expf(v.y - mx);
  }
  #pragma unroll
  for(int off = 32; off; off >>= 1) sum += __shfl_xor(sum, off);
  if(lane == 0){ mrow[gr] = mx; rlrow[gr] = 1.0f / sum; }
}

// ---------------- P·V GEMM: A = exp(S - m) staged on the fly, B = vbT ----------------
__global__ __launch_bounds__(256)
void pv_kernel(const __half* __restrict__ Sc, const float* __restrict__ mrow,
               const float* __restrict__ rlrow, const __bf16* __restrict__ vbT,
               __bf16* __restrict__ att){
  const int b = blockIdx.z, qi = blockIdx.y;
  const long n0 = (long)blockIdx.x * 128;
  const long m0 = (long)qi * 128;
  __shared__ __attribute__((aligned(128))) char As[16384];
  __shared__ __attribute__((aligned(128))) char Bs[16384];
  __shared__ float sM[128], sRl[128];
  const int tid = threadIdx.x, lane = tid & 63, w = tid >> 6;
  if(tid < 128){
    sM [tid] = mrow [b * SEQ + m0 + tid];
    sRl[tid] = rlrow[b * SEQ + m0 + tid];
  }
  const int wr = (w >> 1) * 64, wc = (w & 1) * 64;
  const int rsub = lane >> 3;
  const int r0 = w * 8 + rsub;
  const int kc = (lane & 7) ^ rsub;
  f32x4 acc[4][4] = {};
  const __half* Srow = Sc + (long)b * NTRI * 16384 + (long)(qi * (qi + 1) / 2) * 16384;
  const __bf16* Bv = vbT + n0 * TOK + (long)b * SEQ;
  __syncthreads();                                    // sM/sRl ready
  for(int kt = 0; kt <= qi; ++kt){
    const __half* tile = Srow + (long)kt * 16384;
    #pragma unroll
    for(int half = 0; half < 2; ++half){
      #pragma unroll
      for(int i = 0; i < 4; ++i){
        const int r = i * 32 + r0;
        const __half* hp = tile + r * 128 + half * 64 + kc * 8;
        uint4 raw = *(const uint4*)hp;
        const __half2* h2 = (const __half2*)&raw;
        const float m = sM[r];
        bf16x8 pv;
        #pragma unroll
        for(int j = 0; j < 4; ++j){
          float2 f = __half22float2(h2[j]);
          pv[2 * j]     = (__bf16)__expf(f.x - m);
          pv[2 * j + 1] = (__bf16)__expf(f.y - m);
        }
        *(bf16x8*)(As + (i << 12) + (w << 10) + (lane << 4)) = pv;
      }
      stage_tile(Bv + (long)kt * 128 + half * 64, TOK, Bs, tid);
      __syncthreads();
      mma_tile(As, Bs, lane, wr, wc, acc);
      __syncthreads();
    }
  }
  const int cl = lane & 15, rq = (lane >> 4) * 4;
  #pragma unroll
  for(int i = 0; i < 4; ++i)
    #pragma unroll
    for(int j = 0; j < 4; ++j){
      const long gc = n0 + wc + j * 16 + cl;
      #pragma unroll
      for(int e = 0; e < 4; ++e){
        const int rloc = wr + i * 16 + rq + e;
        float v = acc[i][j][e] * sRl[rloc];
        att[((long)b * SEQ + m0 + rloc) * DIM + gc] = (__bf16)v;
      }
    }
}

// ---------------- launch ----------------
extern "C" void kernel_launch(void* const* d_in, const int* in_sizes, int n_in,
                              void* d_out, int out_size, void* d_ws, size_t ws_size,
                              hipStream_t stream){
  const float* query = (const float*)d_in[0];
  const float* key_  = (const float*)d_in[1];
  const float* value = (const float*)d_in[2];
  const float* Wq = (const float*)d_in[3];
  const float* bq = (const float*)d_in[4];
  const float* Wk = (const float*)d_in[5];
  const float* bk = (const float*)d_in[6];
  const float* Wv = (const float*)d_in[7];
  const float* bv = (const float*)d_in[8];
  const float* Wo = (const float*)d_in[9];
  const float* bo = (const float*)d_in[10];
  // d_in[11] is the causal tril mask; implemented structurally (block-triangular S).

  char* p = (char*)d_ws;
  auto carve = [&](size_t bytes)->char*{
    char* r = p; p += (bytes + 255) & ~(size_t)255; return r;
  };
  const size_t tb = (size_t)TOK * DIM * 2;   // 25.2 MB
  __bf16* xq  = (__bf16*)carve(tb);
  __bf16* xk  = (__bf16*)carve(tb);
  __bf16* xv  = (__bf16*)carve(tb);
  __bf16* qb  = (__bf16*)carve(tb);
  __bf16* kb  = (__bf16*)carve(tb);
  __bf16* vbT = (__bf16*)carve(tb);
  __bf16* Wqb = (__bf16*)carve((size_t)DIM * DIM * 2);
  __bf16* Wkb = (__bf16*)carve((size_t)DIM * DIM * 2);
  __bf16* Wvb = (__bf16*)carve((size_t)DIM * DIM * 2);
  __bf16* Wob = (__bf16*)carve((size_t)DIM * DIM * 2);
  __half* Sc  = (__half*)carve((size_t)BATCH * NTRI * 16384 * 2);  // 69.2 MB
  float*  mrow = (float*)carve((size_t)TOK * 4);
  float*  rlr  = (float*)carve((size_t)TOK * 4);
  __bf16* att = xq;                           // xq dead after q-projection
  if((size_t)(p - (char*)d_ws) > ws_size) return;   // workspace too small: bail

  const long nIn4 = TOK * DIM / 4, nW4 = (long)DIM * DIM / 4;
  const int bIn = (int)((nIn4 + 255) / 256 > 2048 ? 2048 : (nIn4 + 255) / 256);
  const int bW  = (int)((nW4  + 255) / 256);
  cvt_kernel<<<bIn, 256, 0, stream>>>(query, xq, nIn4);
  cvt_kernel<<<bIn, 256, 0, stream>>>(key_,  xk, nIn4);
  cvt_kernel<<<bIn, 256, 0, stream>>>(value, xv, nIn4);
  cvt_kernel<<<bW,  256, 0, stream>>>(Wq, Wqb, nW4);
  cvt_kernel<<<bW,  256, 0, stream>>>(Wk, Wkb, nW4);
  cvt_kernel<<<bW,  256, 0, stream>>>(Wv, Wvb, nW4);
  cvt_kernel<<<bW,  256, 0, stream>>>(Wo, Wob, nW4);

  // Q, K projections: [16384,768] = xq @ Wq^T + bq   -> bf16
  dim3 gProj(DIM / 128, TOK / 128);                   // (6,128)
  gemm_bt<false, false><<<gProj, 256, 0, stream>>>(xq, Wqb, bq, qb, DIM, DIM, DIM, DIM);
  gemm_bt<false, false><<<gProj, 256, 0, stream>>>(xk, Wkb, bk, kb, DIM, DIM, DIM, DIM);
  // V projection, transposed output: vbT[d][tok] = Wv[d]·value[tok] + bv[d]
  dim3 gVT(TOK / 128, DIM / 128);                     // (128,6)
  gemm_bt<false, true><<<gVT, 256, 0, stream>>>(Wvb, xv, bv, vbT, DIM, DIM, DIM, TOK);

  dim3 gQK(NTRI, BATCH);                              // (528,4)
  qk_kernel<<<gQK, 256, 0, stream>>>(qb, kb, Sc);

  rowstats<<<TOK / 4, 256, 0, stream>>>(Sc, mrow, rlr);

  dim3 gPV(DIM / 128, QT, BATCH);                     // (6,32,4)
  pv_kernel<<<gPV, 256, 0, stream>>>(Sc, mrow, rlr, vbT, att);

  // output projection -> fp32 d_out
  gemm_bt<true, false><<<gProj, 256, 0, stream>>>(att, Wob, bo, d_out, DIM, DIM, DIM, DIM);
}

// Round 2
// 329.103 us; speedup vs baseline: 1.3185x; 1.3185x over previous
//
#include <hip/hip_runtime.h>
#include <hip/hip_bf16.h>
#include <stdint.h>

#define DI __device__ __forceinline__

typedef __bf16 bf16x4 __attribute__((ext_vector_type(4)));
typedef __bf16 bf16x8 __attribute__((ext_vector_type(8)));
typedef float  f32x4  __attribute__((ext_vector_type(4)));

static constexpr int  BATCH = 4;
static constexpr int  SEQ   = 4096;
static constexpr int  DIM   = 768;
static constexpr long TOK   = (long)BATCH * SEQ;        // 16384
static constexpr int  QT    = SEQ / 128;                // 32 q-tiles per batch
static constexpr int  NTRI  = QT * (QT + 1) / 2;        // 528 causal tiles
static constexpr float SCALE = 0.0360843918243516150f;  // 1/sqrt(768)

// ---------------- fp32 -> bf16 converts (merged launches) ----------------
__global__ void cvt3_kernel(const float* __restrict__ a, const float* __restrict__ b,
                            const float* __restrict__ c, __bf16* __restrict__ oa,
                            __bf16* __restrict__ ob, __bf16* __restrict__ oc, long n4){
  const float* in  = blockIdx.y == 0 ? a : blockIdx.y == 1 ? b : c;
  __bf16*      out = blockIdx.y == 0 ? oa : blockIdx.y == 1 ? ob : oc;
  long i = (long)blockIdx.x * blockDim.x + threadIdx.x;
  const long stride = (long)gridDim.x * blockDim.x;
  for(; i < n4; i += stride){
    float4 v = ((const float4*)in)[i];
    bf16x4 o = { (__bf16)v.x, (__bf16)v.y, (__bf16)v.z, (__bf16)v.w };
    ((bf16x4*)out)[i] = o;
  }
}
__global__ void cvt4_kernel(const float* __restrict__ a, const float* __restrict__ b,
                            const float* __restrict__ c, const float* __restrict__ d,
                            __bf16* __restrict__ oa, __bf16* __restrict__ ob,
                            __bf16* __restrict__ oc, __bf16* __restrict__ od, long n4){
  const float* in  = blockIdx.y == 0 ? a : blockIdx.y == 1 ? b : blockIdx.y == 2 ? c : d;
  __bf16*      out = blockIdx.y == 0 ? oa : blockIdx.y == 1 ? ob : blockIdx.y == 2 ? oc : od;
  long i = (long)blockIdx.x * blockDim.x + threadIdx.x;
  const long stride = (long)gridDim.x * blockDim.x;
  for(; i < n4; i += stride){
    float4 v = ((const float4*)in)[i];
    bf16x4 o = { (__bf16)v.x, (__bf16)v.y, (__bf16)v.z, (__bf16)v.w };
    ((bf16x4*)out)[i] = o;
  }
}

// ---------------- shared GEMM machinery ----------------
// LDS tile: [R rows][64 bf16 = 8 chunks of 16B], chunk XOR-swizzled by (row&7).
DI int swz_off(int r, int c){ return (r << 7) + ((c ^ (r & 7)) << 4); }

// Stage R x 64 bf16 tile from row-major src (leading dim ld) via global_load_lds,
// pre-swizzled global source (m173 pattern), linear LDS dest.
template<int NT, int R>
DI void stage(const __bf16* __restrict__ src, long ld, char* lds, int tid){
  const int w = tid >> 6, l = tid & 63;
  const int rsub = l >> 3;
  const int kc   = (l & 7) ^ rsub;
  const __bf16* g = src + (long)(w * 8 + rsub) * ld + kc * 8;
  char* d = lds + (w << 10);
  constexpr int RPC = (NT / 64) * 8;   // rows covered per call round
  #pragma unroll
  for(int i = 0; i < R / RPC; ++i){
    __builtin_amdgcn_global_load_lds(
        (const __attribute__((address_space(1))) void*)(g + (long)(i * RPC) * ld),
        (__attribute__((address_space(3))) void*)(d + i * RPC * 128), 16, 0, 0);
  }
}

DI bf16x8 frag_ld(const char* lds, int row, int c){
  return *(const bf16x8*)(lds + swz_off(row, c));
}

// One K=64 step: 32 MFMAs per wave (4x4 frags x 2 k-halves). Wave output 64x64.
DI void mma_tile(const char* As, const char* Bs, int lane, int wr, int wc, f32x4 acc[4][4]){
  #pragma unroll
  for(int kk = 0; kk < 2; ++kk){
    const int c = kk * 4 + (lane >> 4);
    bf16x8 a[4], b[4];
    #pragma unroll
    for(int i = 0; i < 4; ++i) a[i] = frag_ld(As, wr + i * 16 + (lane & 15), c);
    #pragma unroll
    for(int j = 0; j < 4; ++j) b[j] = frag_ld(Bs, wc + j * 16 + (lane & 15), c);
    #pragma unroll
    for(int i = 0; i < 4; ++i)
      #pragma unroll
      for(int j = 0; j < 4; ++j)
        acc[i][j] = __builtin_amdgcn_mfma_f32_16x16x32_bf16(a[i], b[j], acc[i][j], 0, 0, 0);
  }
}

// ---------------- 128x256 GEMM, 8 waves: C[m][n] = sum_k A[m][k]*B[n][k] + bias ----
// grid: x = n-tile (256 wide), y = m-tile (128). K multiple of 64.
template<bool OUTF32, bool BIASM>
__global__ __launch_bounds__(512)
void gemm256_bt(const __bf16* __restrict__ A, const __bf16* __restrict__ B,
                const float* __restrict__ bias, void* __restrict__ C,
                int K, long lda, long ldb, long ldc){
  __shared__ __attribute__((aligned(128))) char As[16384];
  __shared__ __attribute__((aligned(128))) char Bs[32768];
  const int tid = threadIdx.x, lane = tid & 63, w = tid >> 6;
  const int wr = (w >> 2) * 64, wc = (w & 3) * 64;
  const long m0 = (long)blockIdx.y * 128, n0 = (long)blockIdx.x * 256;
  f32x4 acc[4][4] = {};
  for(int k0 = 0; k0 < K; k0 += 64){
    stage<512, 128>(A + m0 * lda + k0, lda, As, tid);
    stage<512, 256>(B + n0 * ldb + k0, ldb, Bs, tid);
    __syncthreads();
    mma_tile(As, Bs, lane, wr, wc, acc);
    __syncthreads();
  }
  const int cl = lane & 15, rq = (lane >> 4) * 4;
  #pragma unroll
  for(int i = 0; i < 4; ++i)
    #pragma unroll
    for(int j = 0; j < 4; ++j){
      const long gc = n0 + wc + j * 16 + cl;
      #pragma unroll
      for(int e = 0; e < 4; ++e){
        const long gr = m0 + wr + i * 16 + rq + e;
        float v = acc[i][j][e] + (BIASM ? bias[gr] : bias[gc]);
        if(OUTF32) ((float*)C)[gr * ldc + gc] = v;
        else       ((__bf16*)C)[gr * ldc + gc] = (__bf16)v;
      }
    }
}

// ---------------- QK^T, 256x128 tiles, fused exp epilogue -> compact bf16 P ----------
__global__ __launch_bounds__(512)
void qk_kernel(const __bf16* __restrict__ qb, const __bf16* __restrict__ kb,
               __bf16* __restrict__ Pc){
  const int b = blockIdx.y;
  const int t2 = blockIdx.x;                      // 0..271: (Qi, ki), ki <= 2*Qi+1
  int Qi = (int)((sqrtf(4.0f * t2 + 1.0f) - 1.0f) * 0.5f);
  while((Qi + 1) * (Qi + 2) <= t2) Qi++;
  while(Qi * (Qi + 1) > t2) Qi--;
  const int ki = t2 - Qi * (Qi + 1);
  const __bf16* Aq = qb + ((long)b * SEQ + Qi * 256) * DIM;
  const __bf16* Bk = kb + ((long)b * SEQ + ki * 128) * DIM;
  __shared__ __attribute__((aligned(128))) char As[32768];
  __shared__ __attribute__((aligned(128))) char Bs[16384];
  const int tid = threadIdx.x, lane = tid & 63, w = tid >> 6;
  const int wr = (w >> 1) * 64, wc = (w & 1) * 64;
  f32x4 acc[4][4] = {};
  for(int k0 = 0; k0 < DIM; k0 += 64){
    stage<512, 256>(Aq + k0, DIM, As, tid);
    stage<512, 128>(Bk + k0, DIM, Bs, tid);
    __syncthreads();
    mma_tile(As, Bs, lane, wr, wc, acc);
    __syncthreads();
  }
  const int cl = lane & 15, rq = (lane >> 4) * 4;
  #pragma unroll
  for(int i = 0; i < 4; ++i){
    const int rbase = wr + i * 16;
    const int qi = 2 * Qi + (rbase >> 7);
    if(ki > qi) continue;                         // fully-masked half-tile: not stored
    const bool diag = (ki == qi);
    __bf16* tile = Pc + ((long)b * NTRI + (long)qi * (qi + 1) / 2 + ki) * 16384;
    #pragma unroll
    for(int j = 0; j < 4; ++j){
      const int c = wc + j * 16 + cl;
      #pragma unroll
      for(int e = 0; e < 4; ++e){
        const int rloc = (rbase + rq + e) & 127;
        float p = (diag && c > rloc) ? 0.0f
                  : __expf(fminf(acc[i][j][e] * SCALE, 30.0f));
        tile[rloc * 128 + c] = (__bf16)p;
      }
    }
  }
}

// ---------------- per-row 1/sum over compact bf16 P ----------------
__global__ void rowsum(const __bf16* __restrict__ Pc, float* __restrict__ rlrow){
  const int gr = blockIdx.x * 4 + (threadIdx.x >> 6);   // one wave per row
  const int lane = threadIdx.x & 63;
  const int b = gr >> 12, r = gr & 4095;
  const int qi = r >> 7, rloc = r & 127;
  const __bf16* base = Pc + ((long)b * NTRI + (long)qi * (qi + 1) / 2) * 16384
                       + rloc * 128;
  float s = 0.f;
  for(int ki = 0; ki <= qi; ++ki){
    uint32_t u = *(const uint32_t*)(base + (long)ki * 16384 + lane * 2);
    s += __uint_as_float(u << 16) + __uint_as_float(u & 0xffff0000u);
  }
  #pragma unroll
  for(int off = 32; off; off >>= 1) s += __shfl_xor(s, off);
  if(lane == 0) rlrow[gr] = 1.0f / s;
}

// ---------------- P·V: pure 128x256 GEMM over compact P, scaled by 1/l ------------
__global__ __launch_bounds__(512)
void pv_kernel(const __bf16* __restrict__ Pc, const float* __restrict__ rlrow,
               const __bf16* __restrict__ vbT, __bf16* __restrict__ att){
  const int b = blockIdx.z, qi = 31 - blockIdx.y;       // long-K blocks first
  const long n0 = (long)blockIdx.x * 256;
  __shared__ __attribute__((aligned(128))) char As[16384];
  __shared__ __attribute__((aligned(128))) char Bs[32768];
  __shared__ float sRl[128];
  const int tid = threadIdx.x, lane = tid & 63, w = tid >> 6;
  const int wr = (w >> 2) * 64, wc = (w & 3) * 64;
  if(tid < 128) sRl[tid] = rlrow[b * SEQ + qi * 128 + tid];
  f32x4 acc[4][4] = {};
  const __bf16* Pq = Pc + ((long)b * NTRI + (long)qi * (qi + 1) / 2) * 16384;
  const __bf16* Bv = vbT + n0 * TOK + (long)b * SEQ;
  __syncthreads();                                      // sRl ready
  for(int kt = 0; kt <= qi; ++kt){
    #pragma unroll
    for(int half = 0; half < 2; ++half){
      stage<512, 128>(Pq + (long)kt * 16384 + half * 64, 128, As, tid);
      stage<512, 256>(Bv + (long)kt * 128 + half * 64, TOK, Bs, tid);
      __syncthreads();
      mma_tile(As, Bs, lane, wr, wc, acc);
      __syncthreads();
    }
  }
  const int cl = lane & 15, rq = (lane >> 4) * 4;
  #pragma unroll
  for(int i = 0; i < 4; ++i)
    #pragma unroll
    for(int j = 0; j < 4; ++j){
      const long gc = n0 + wc + j * 16 + cl;
      #pragma unroll
      for(int e = 0; e < 4; ++e){
        const int rloc = wr + i * 16 + rq + e;
        float v = acc[i][j][e] * sRl[rloc];
        att[((long)b * SEQ + qi * 128 + rloc) * DIM + gc] = (__bf16)v;
      }
    }
}

// ---------------- launch ----------------
extern "C" void kernel_launch(void* const* d_in, const int* in_sizes, int n_in,
                              void* d_out, int out_size, void* d_ws, size_t ws_size,
                              hipStream_t stream){
  const float* query = (const float*)d_in[0];
  const float* key_  = (const float*)d_in[1];
  const float* value = (const float*)d_in[2];
  const float* Wq = (const float*)d_in[3];
  const float* bq = (const float*)d_in[4];
  const float* Wk = (const float*)d_in[5];
  const float* bk = (const float*)d_in[6];
  const float* Wv = (const float*)d_in[7];
  const float* bv = (const float*)d_in[8];
  const float* Wo = (const float*)d_in[9];
  const float* bo = (const float*)d_in[10];
  // d_in[11]: causal tril mask — implemented structurally (block-triangular P).

  char* p = (char*)d_ws;
  auto carve = [&](size_t bytes)->char*{
    char* r = p; p += (bytes + 255) & ~(size_t)255; return r;
  };
  const size_t tb = (size_t)TOK * DIM * 2;   // 25.2 MB
  __bf16* xq  = (__bf16*)carve(tb);
  __bf16* xk  = (__bf16*)carve(tb);
  __bf16* xv  = (__bf16*)carve(tb);
  __bf16* qb  = (__bf16*)carve(tb);
  __bf16* kb  = (__bf16*)carve(tb);
  __bf16* vbT = (__bf16*)carve(tb);
  __bf16* Wqb = (__bf16*)carve((size_t)DIM * DIM * 2);
  __bf16* Wkb = (__bf16*)carve((size_t)DIM * DIM * 2);
  __bf16* Wvb = (__bf16*)carve((size_t)DIM * DIM * 2);
  __bf16* Wob = (__bf16*)carve((size_t)DIM * DIM * 2);
  __bf16* Pc  = (__bf16*)carve((size_t)BATCH * NTRI * 16384 * 2);  // 69.2 MB
  float*  rlr = (float*)carve((size_t)TOK * 4);
  __bf16* att = xq;                           // xq dead after q-projection
  if((size_t)(p - (char*)d_ws) > ws_size) return;

  const long nIn4 = TOK * DIM / 4, nW4 = (long)DIM * DIM / 4;
  dim3 g3(2048, 3), g4((unsigned)((nW4 + 255) / 256), 4);
  cvt3_kernel<<<g3, 256, 0, stream>>>(query, key_, value, xq, xk, xv, nIn4);
  cvt4_kernel<<<g4, 256, 0, stream>>>(Wq, Wk, Wv, Wo, Wqb, Wkb, Wvb, Wob, nW4);

  // Q, K projections: [16384,768] = x @ W^T + b  -> bf16
  dim3 gProj(DIM / 256, TOK / 128);                    // (3,128)
  gemm256_bt<false, false><<<gProj, 512, 0, stream>>>(xq, Wqb, bq, qb, DIM, DIM, DIM, DIM);
  gemm256_bt<false, false><<<gProj, 512, 0, stream>>>(xk, Wkb, bk, kb, DIM, DIM, DIM, DIM);
  // V projection, transposed output: vbT[d][tok] = Wv[d]·value[tok] + bv[d]
  dim3 gVT(TOK / 256, DIM / 128);                      // (64,6)
  gemm256_bt<false, true><<<gVT, 512, 0, stream>>>(Wvb, xv, bv, vbT, DIM, DIM, DIM, TOK);

  dim3 gQK(272, BATCH);                                // 256-row q-tiles, causal
  qk_kernel<<<gQK, 512, 0, stream>>>(qb, kb, Pc);

  rowsum<<<TOK / 4, 256, 0, stream>>>(Pc, rlr);

  dim3 gPV(DIM / 256, QT, BATCH);                      // (3,32,4)
  pv_kernel<<<gPV, 512, 0, stream>>>(Pc, rlr, vbT, att);

  // output projection -> fp32 d_out
  gemm256_bt<true, false><<<gProj, 512, 0, stream>>>(att, Wob, bo, d_out, DIM, DIM, DIM, DIM);
}